// Round 1
// baseline (123.159 us; speedup 1.0000x reference)
//
#include <hip/hip_runtime.h>
#include <stdint.h>

#define TT 64
#define BB 128
#define VV 4880
#define NF4 (VV / 4)          // 1220 float4 per row
#define NROWS (TT * BB)       // 8192
#define LOG_EPS_F 1e-8f
#define CAP 256
#define NBUCKET 64
#define NQ 9
#define THR0 0.98f

// Pack (value, row-local idx) so that u64 max-compare == (value desc, idx asc).
// y_hat > 0 so float bits are monotonic in value. idx < 4880 fits in 13 bits.
__device__ __forceinline__ uint64_t mkkey(float v, int idx) {
  return ((uint64_t)__float_as_uint(v) << 13) | (uint64_t)(8191 - idx);
}

__global__ __launch_bounds__(64) void pass_kernel(
    const float* __restrict__ yhat, const float* __restrict__ yy,
    const float* __restrict__ length, float* __restrict__ bucket) {
  __shared__ uint64_t cand[CAP];
  __shared__ int cnt_sh;

  const int row  = blockIdx.x;          // row = t*B + b
  const int lane = threadIdx.x;         // 0..63
  const int b    = row & (BB - 1);
  const float4* h4 = (const float4*)(yhat + (size_t)row * VV);
  const float4* y4 = (const float4*)(yy   + (size_t)row * VV);

  float logsum = 0.0f;   // sum of log(selected); ce = -logsum
  int   npos   = 0;
  float thr = THR0;
  int   cnt = 0;

  for (int attempt = 0; attempt < 6; ++attempt) {
    if (lane == 0) cnt_sh = 0;
    __syncthreads();
    const bool first = (attempt == 0);

    for (int f = lane; f < NF4; f += 64) {
      float4 h = h4[f];
      if (first) {
        float4 yv = y4[f];
        float a0 = (yv.x != 0.0f) ? (h.x + LOG_EPS_F) : (1.0f - h.x + LOG_EPS_F);
        float a1 = (yv.y != 0.0f) ? (h.y + LOG_EPS_F) : (1.0f - h.y + LOG_EPS_F);
        float a2 = (yv.z != 0.0f) ? (h.z + LOG_EPS_F) : (1.0f - h.z + LOG_EPS_F);
        float a3 = (yv.w != 0.0f) ? (h.w + LOG_EPS_F) : (1.0f - h.w + LOG_EPS_F);
        logsum += __logf(a0) + __logf(a1) + __logf(a2) + __logf(a3);
        npos += (yv.x != 0.0f) + (yv.y != 0.0f) + (yv.z != 0.0f) + (yv.w != 0.0f);
      }
      const int base = 4 * f;
      if (h.x > thr) { int s = atomicAdd(&cnt_sh, 1); if (s < CAP) cand[s] = mkkey(h.x, base); }
      if (h.y > thr) { int s = atomicAdd(&cnt_sh, 1); if (s < CAP) cand[s] = mkkey(h.y, base + 1); }
      if (h.z > thr) { int s = atomicAdd(&cnt_sh, 1); if (s < CAP) cand[s] = mkkey(h.z, base + 2); }
      if (h.w > thr) { int s = atomicAdd(&cnt_sh, 1); if (s < CAP) cand[s] = mkkey(h.w, base + 3); }
    }
    __syncthreads();
    cnt = cnt_sh;
    if (cnt >= 20 && cnt <= CAP) break;        // wave-uniform (LDS value)
    if (cnt < 20) thr = 1.0f - (1.0f - thr) * 4.0f;     // widen tail
    else          thr = 1.0f - (1.0f - thr) * 0.25f;    // tighten tail
    __syncthreads();
  }
  if (cnt > CAP) cnt = CAP;

  // ---- top-20 extraction: 20 x (local max of 4 regs + wave max-reduce) ----
  uint64_t k0 = 0, k1 = 0, k2 = 0, k3 = 0;
  if (lane       < cnt) k0 = cand[lane];
  if (lane + 64  < cnt) k1 = cand[lane + 64];
  if (lane + 128 < cnt) k2 = cand[lane + 128];
  if (lane + 192 < cnt) k3 = cand[lane + 192];

  uint64_t win = 0;
  for (int r = 0; r < 20; ++r) {
    uint64_t a = (k0 > k1) ? k0 : k1;
    uint64_t c = (k2 > k3) ? k2 : k3;
    uint64_t m = (a > c) ? a : c;
    #pragma unroll
    for (int s = 32; s >= 1; s >>= 1) {
      unsigned long long o = __shfl_xor((unsigned long long)m, s, 64);
      if (o > m) m = (uint64_t)o;
    }
    if      (k0 == m) k0 = 0;
    else if (k1 == m) k1 = 0;
    else if (k2 == m) k2 = 0;
    else if (k3 == m) k3 = 0;
    if (lane == r) win = m;
  }

  // lane r holds the rank-r element; check its label
  bool hit = false;
  if (lane < 20 && win != 0) {
    int idx = 8191 - (int)(win & 8191u);
    hit = (yy[(size_t)row * VV + idx] != 0.0f);
  }
  unsigned long long mask = __ballot(hit);

  // ---- wave reductions for ce and n_pos ----
  #pragma unroll
  for (int s = 32; s >= 1; s >>= 1) {
    logsum += __shfl_xor(logsum, s, 64);
    npos   += __shfl_xor(npos, s, 64);
  }

  if (lane == 0) {
    float* bk = bucket + (size_t)(row & (NBUCKET - 1)) * NQ;
    float ce = -logsum / (length[b] * (float)BB);
    atomicAdd(bk + 0, ce);
    atomicAdd(bk + 1, (float)__popcll(mask & 0x1Full));     // k=5
    atomicAdd(bk + 2, (float)__popcll(mask & 0x3FFull));    // k=10
    atomicAdd(bk + 3, (float)__popcll(mask & 0x7FFFull));   // k=15
    atomicAdd(bk + 4, (float)__popcll(mask & 0xFFFFFull));  // k=20
    float np = (float)npos;
    atomicAdd(bk + 5, np);
    atomicAdd(bk + 6, np);
    atomicAdd(bk + 7, np);
    atomicAdd(bk + 8, np);
  }
}

__global__ __launch_bounds__(64) void reduce_kernel(const float* __restrict__ bucket,
                                                    float* __restrict__ out) {
  const int lane = threadIdx.x;  // 64 lanes, one bucket each
  float acc[NQ];
  #pragma unroll
  for (int q = 0; q < NQ; ++q) acc[q] = bucket[lane * NQ + q];
  #pragma unroll
  for (int q = 0; q < NQ; ++q) {
    #pragma unroll
    for (int s = 32; s >= 1; s >>= 1) acc[q] += __shfl_xor(acc[q], s, 64);
  }
  if (lane == 0) {
    #pragma unroll
    for (int q = 0; q < NQ; ++q) out[q] = acc[q];
  }
}

extern "C" void kernel_launch(void* const* d_in, const int* in_sizes, int n_in,
                              void* d_out, int out_size, void* d_ws, size_t ws_size,
                              hipStream_t stream) {
  const float* yhat = (const float*)d_in[0];
  const float* yy   = (const float*)d_in[1];
  const float* len  = (const float*)d_in[2];
  float* out    = (float*)d_out;
  float* bucket = (float*)d_ws;   // NBUCKET*NQ floats = 2304 B

  hipMemsetAsync(bucket, 0, NBUCKET * NQ * sizeof(float), stream);
  pass_kernel<<<NROWS, 64, 0, stream>>>(yhat, yy, len, bucket);
  reduce_kernel<<<1, 64, 0, stream>>>(bucket, out);
}

// Round 2
// 95.175 us; speedup vs baseline: 1.2940x; 1.2940x over previous
//
#include <hip/hip_runtime.h>
#include <stdint.h>

#define TT 64
#define BB 128
#define VV 4880
#define NF4 (VV / 4)          // 1220 float4 per row
#define NROWS (TT * BB)       // 8192
#define LOG_EPS_F 1e-8f
#define CAP 256               // max stored candidates per row
#define PCAP 64               // max stored positive candidates per row
#define NBUCKET 64
#define NQ 9
#define THR0 0.98f

// Pack (value, row-local idx) so that u64 max-compare == (value desc, idx asc).
// y_hat > 0 so float bits are monotonic in value. idx < 4880 fits in 13 bits.
__device__ __forceinline__ uint64_t mkkey(float v, int idx) {
  return ((uint64_t)__float_as_uint(v) << 13) | (uint64_t)(8191 - idx);
}

__global__ __launch_bounds__(256) void pass_kernel(
    const float* __restrict__ yhat, const float* __restrict__ yy,
    const float* __restrict__ length, float* __restrict__ bucket) {
  __shared__ uint64_t cand[4][CAP];
  __shared__ uint64_t pcand[4][PCAP];
  __shared__ int cnt_sh[4];
  __shared__ int pcnt_sh[4];
  __shared__ int retry_sh;

  const int wid  = threadIdx.x >> 6;    // wave 0..3
  const int lane = threadIdx.x & 63;
  const int row  = blockIdx.x * 4 + wid;   // row = t*B + b
  const int b    = row & (BB - 1);
  const float4* h4 = (const float4*)(yhat + (size_t)row * VV);
  const float4* y4 = (const float4*)(yy   + (size_t)row * VV);

  if (threadIdx.x < 4) { cnt_sh[threadIdx.x] = 0; pcnt_sh[threadIdx.x] = 0; }
  if (threadIdx.x == 0) retry_sh = 0;
  __syncthreads();

  float logsum = 0.0f;
  int   npos   = 0;
  float thr    = THR0;

  // candidate insert (+ positive-candidate tracking)
  auto proc1 = [&](float v, float yv, int idx) {
    if (v > thr) {
      uint64_t key = mkkey(v, idx);
      int s = atomicAdd(&cnt_sh[wid], 1);
      if (s < CAP) cand[wid][s] = key;
      if (yv != 0.0f) {
        int sp = atomicAdd(&pcnt_sh[wid], 1);
        if (sp < PCAP) pcand[wid][sp] = key;
      }
    }
  };
  auto bce1 = [&](float h, float yv) {
    float a = (yv != 0.0f) ? (h + LOG_EPS_F) : (1.0f - h + LOG_EPS_F);
    logsum += __logf(a);
    npos += (yv != 0.0f);
  };
  auto full1 = [&](float4 h, float4 v, int base) {
    bce1(h.x, v.x); bce1(h.y, v.y); bce1(h.z, v.z); bce1(h.w, v.w);
    proc1(h.x, v.x, base); proc1(h.y, v.y, base + 1);
    proc1(h.z, v.z, base + 2); proc1(h.w, v.w, base + 3);
  };

  // ---- main scan: 19 full iters (unroll 4x with batched loads) + tail ----
  #pragma unroll 1
  for (int i = 0; i < 16; i += 4) {
    const int f = lane + 64 * i;
    float4 h0 = h4[f], h1 = h4[f + 64], h2 = h4[f + 128], h3 = h4[f + 192];
    float4 v0 = y4[f], v1 = y4[f + 64], v2 = y4[f + 128], v3 = y4[f + 192];
    full1(h0, v0, 4 * f);
    full1(h1, v1, 4 * (f + 64));
    full1(h2, v2, 4 * (f + 128));
    full1(h3, v3, 4 * (f + 192));
  }
  #pragma unroll
  for (int i = 16; i < 19; ++i) {
    const int f = lane + 64 * i;
    float4 h0 = h4[f], v0 = y4[f];
    full1(h0, v0, 4 * f);
  }
  if (lane < 4) {
    const int f = 1216 + lane;
    float4 h0 = h4[f], v0 = y4[f];
    full1(h0, v0, 4 * f);
  }
  __syncthreads();

  int  cnt  = cnt_sh[wid];
  int  pcnt = pcnt_sh[wid];
  bool done = (cnt >= 20 && cnt <= CAP);
  if (!done && lane == 0) retry_sh = 1;
  __syncthreads();

  // ---- cold retry path (block-uniform loop; never taken on this data) ----
  if (retry_sh) {
    for (int attempt = 1; attempt < 6; ++attempt) {
      if (!done) thr = (cnt < 20) ? 1.0f - (1.0f - thr) * 4.0f
                                  : 1.0f - (1.0f - thr) * 0.25f;
      __syncthreads();
      if (!done && lane == 0) { cnt_sh[wid] = 0; pcnt_sh[wid] = 0; }
      if (threadIdx.x == 0) retry_sh = 0;
      __syncthreads();
      if (!done) {
        for (int f = lane; f < NF4; f += 64) {
          float4 h = h4[f], v = y4[f];
          proc1(h.x, v.x, 4 * f);     proc1(h.y, v.y, 4 * f + 1);
          proc1(h.z, v.z, 4 * f + 2); proc1(h.w, v.w, 4 * f + 3);
        }
      }
      __syncthreads();
      if (!done) {
        cnt = cnt_sh[wid]; pcnt = pcnt_sh[wid];
        done = (cnt >= 20 && cnt <= CAP);
      }
      if (!done && lane == 0) retry_sh = 1;
      __syncthreads();
      if (!retry_sh) break;
    }
  }
  if (cnt > CAP)  cnt  = CAP;
  if (pcnt > PCAP) pcnt = PCAP;

  // ---- rank each positive candidate: rank = #{cand keys > key(p)} ----
  float tpk[4] = {0.f, 0.f, 0.f, 0.f};
  for (int p = 0; p < pcnt; ++p) {
    uint64_t pk = pcand[wid][p];
    int c = 0;
    for (int j = lane; j < cnt; j += 64) c += (cand[wid][j] > pk) ? 1 : 0;
    #pragma unroll
    for (int s = 32; s >= 1; s >>= 1) c += __shfl_xor(c, s, 64);
    tpk[0] += (c < 5);  tpk[1] += (c < 10);
    tpk[2] += (c < 15); tpk[3] += (c < 20);
  }

  // ---- wave reductions for ce and n_pos ----
  #pragma unroll
  for (int s = 32; s >= 1; s >>= 1) {
    logsum += __shfl_xor(logsum, s, 64);
    npos   += __shfl_xor(npos, s, 64);
  }

  if (lane == 0) {
    float* bk = bucket + (size_t)(row & (NBUCKET - 1)) * NQ;
    float ce = -logsum / (length[b] * (float)BB);
    atomicAdd(bk + 0, ce);
    atomicAdd(bk + 1, tpk[0]);
    atomicAdd(bk + 2, tpk[1]);
    atomicAdd(bk + 3, tpk[2]);
    atomicAdd(bk + 4, tpk[3]);
    float np = (float)npos;
    atomicAdd(bk + 5, np);
    atomicAdd(bk + 6, np);
    atomicAdd(bk + 7, np);
    atomicAdd(bk + 8, np);
  }
}

__global__ __launch_bounds__(64) void reduce_kernel(const float* __restrict__ bucket,
                                                    float* __restrict__ out) {
  const int lane = threadIdx.x;  // 64 lanes, one bucket each
  float acc[NQ];
  #pragma unroll
  for (int q = 0; q < NQ; ++q) acc[q] = bucket[lane * NQ + q];
  #pragma unroll
  for (int q = 0; q < NQ; ++q) {
    #pragma unroll
    for (int s = 32; s >= 1; s >>= 1) acc[q] += __shfl_xor(acc[q], s, 64);
  }
  if (lane == 0) {
    #pragma unroll
    for (int q = 0; q < NQ; ++q) out[q] = acc[q];
  }
}

extern "C" void kernel_launch(void* const* d_in, const int* in_sizes, int n_in,
                              void* d_out, int out_size, void* d_ws, size_t ws_size,
                              hipStream_t stream) {
  const float* yhat = (const float*)d_in[0];
  const float* yy   = (const float*)d_in[1];
  const float* len  = (const float*)d_in[2];
  float* out    = (float*)d_out;
  float* bucket = (float*)d_ws;   // NBUCKET*NQ floats = 2304 B

  hipMemsetAsync(bucket, 0, NBUCKET * NQ * sizeof(float), stream);
  pass_kernel<<<NROWS / 4, 256, 0, stream>>>(yhat, yy, len, bucket);
  reduce_kernel<<<1, 64, 0, stream>>>(bucket, out);
}